// Round 9
// baseline (1280.874 us; speedup 1.0000x reference)
//
#include <hip/hip_runtime.h>

typedef _Float16 f16;
typedef _Float16 half8 __attribute__((ext_vector_type(8)));
typedef _Float16 half4v __attribute__((ext_vector_type(4)));
typedef float f32x4 __attribute__((ext_vector_type(4)));

// x: [128][512][128] f32, alpha: [128] f32, A: [128][128][128] f32 (i,j,k), Omega: [128][32] f32
// out: [128][32] f32
// Phase 1: B[q][i][k] = sum_j A[i][j][k] * x[n(q), t(q), j]  (fp16 store, fp32 acc)
// Phase 2: h <- B_t^T h sequentially, fp32 -- ONE WAVE PER BATCH, zero barriers.
// Overlap: dispatch D_c = chain(c) [blocks 0..31, 4 waves = 4 batches each]
//          + gemm(c+1) [blocks 32..]; stream order is the only synchronization.

// ---------- convert x -> fp16 ----------
__global__ void k_cvt_x(const float* __restrict__ in, f16* __restrict__ out) {
    int idx = blockIdx.x * blockDim.x + threadIdx.x;
    float4 v = ((const float4*)in)[idx];
    half4v o;
    o[0] = (f16)v.x; o[1] = (f16)v.y; o[2] = (f16)v.z; o[3] = (f16)v.w;
    ((half4v*)out)[idx] = o;
}

// ---------- transpose-convert A: Af2[i][k][j] = A[i][j][k] ----------
__global__ void k_cvt_A(const float* __restrict__ A, f16* __restrict__ Af2) {
    int o = blockIdx.x * blockDim.x + threadIdx.x;
    int i = o >> 14;
    int k = (o >> 7) & 127;
    int j = o & 127;
    Af2[o] = (f16)A[(i << 14) + (j << 7) + k];
}

// ================= gemm body (R4, proven: VGPR 88, 0 LDS conflicts) ============
__device__ __forceinline__
void gemm_body(f16* lA, f16* lX, const f16* __restrict__ Af2, const f16* __restrict__ Xh,
               f16* __restrict__ B, int t0, int logTc, int qtile, int i, int tid) {
    const int row = tid >> 4;
    const int ch = tid & 15;
    const int Tcm1 = (1 << logTc) - 1;

    {
        const f16* srcA = Af2 + ((size_t)i << 14);
#pragma unroll
        for (int r = 0; r < 128; r += 16) {
            int rr = row + r;
            uint4 v = *(const uint4*)(srcA + (rr << 7) + (ch << 3));
            *(uint4*)(&lA[(rr << 7) + ((ch ^ (rr & 15)) << 3)]) = v;
        }
#pragma unroll
        for (int r = 0; r < 128; r += 16) {
            int rr = row + r;
            int qr = (qtile << 7) + rr;
            int n = qr >> logTc;
            int trel = qr & Tcm1;
            const f16* srcX = Xh + (((size_t)(n << 9) + t0 + trel) << 7);
            uint4 v = *(const uint4*)(srcX + (ch << 3));
            *(uint4*)(&lX[(rr << 7) + ((ch ^ (rr & 15)) << 3)]) = v;
        }
    }
    __syncthreads();

    const int wave = tid >> 6;
    const int lane = tid & 63;
    const int l15 = lane & 15;
    const int l4 = lane >> 4;
    f32x4 acc[8][2] = {};

#pragma unroll
    for (int ks = 0; ks < 4; ++ks) {
        const int c = (ks << 2) + l4;
        half8 afr[8], bfr[2];
#pragma unroll
        for (int mt = 0; mt < 8; ++mt) {
            int rowA = (mt << 4) + l15;
            afr[mt] = *(const half8*)(&lA[(rowA << 7) + ((c ^ l15) << 3)]);
        }
#pragma unroll
        for (int qt = 0; qt < 2; ++qt) {
            int rowX = (wave << 5) + (qt << 4) + l15;
            bfr[qt] = *(const half8*)(&lX[(rowX << 7) + ((c ^ l15) << 3)]);
        }
#pragma unroll
        for (int mt = 0; mt < 8; ++mt)
#pragma unroll
            for (int qt = 0; qt < 2; ++qt)
                acc[mt][qt] = __builtin_amdgcn_mfma_f32_16x16x32_f16(
                    afr[mt], bfr[qt], acc[mt][qt], 0, 0, 0);
    }

    __syncthreads();
    f16* stage = lA;
#pragma unroll
    for (int mt = 0; mt < 8; ++mt)
#pragma unroll
        for (int qt = 0; qt < 2; ++qt) {
            int q = (wave << 5) + (qt << 4) + l15;
            int chunk = (mt << 1) + (l4 >> 1);
            int hf = l4 & 1;
            half4v o;
            o[0] = (f16)acc[mt][qt][0];
            o[1] = (f16)acc[mt][qt][1];
            o[2] = (f16)acc[mt][qt][2];
            o[3] = (f16)acc[mt][qt][3];
            *(half4v*)(&stage[(q << 7) + (((chunk ^ l15) << 3) + (hf << 2))]) = o;
        }
    __syncthreads();
    {
        const int lr = lane >> 4;
        const int lc = lane & 15;
#pragma unroll
        for (int it = 0; it < 8; ++it) {
            int q = (wave << 5) + (it << 2) + lr;
            uint4 v = *(const uint4*)(&stage[(q << 7) + ((lc ^ (q & 15)) << 3)]);
            size_t qg = (size_t)((qtile << 7) + q);
            *(uint4*)(B + (qg << 14) + (i << 7) + (lc << 3)) = v;
        }
    }
}

// ================= chain: one wave per batch, zero barriers =================
// lane = iq(0..3, 32 i's each) x kg(0..15, 8 k's). Per step: 32 coalesced
// dwordx4 B loads, fp32 fma, shfl_xor(16/32) reduce, h via 512B wave-private LDS.
__device__ __forceinline__
void chain_wave(float* hB, const f16* __restrict__ B,
                float* __restrict__ hstate, const float* __restrict__ alpha,
                const float* __restrict__ Om, float* __restrict__ out,
                int Tc, int first, int last, int n, int lane) {
    const int iq = lane >> 4;       // 0..3
    const int kg = lane & 15;       // 0..15

    if (first) {
        hB[lane] = alpha[lane];
        hB[lane + 64] = alpha[lane + 64];
    } else {
        const float* hs = hstate + (n << 7);
        hB[lane] = hs[lane];
        hB[lane + 64] = hs[lane + 64];
    }
    // single wave: no barrier needed anywhere below

    const f16* bbat = B + (((size_t)n * Tc) << 14) + (iq << 12) + (kg << 3);

    for (int t = 0; t < Tc; ++t) {
        const f16* bt = bbat + ((size_t)t << 14);
        float4 hv[8];
#pragma unroll
        for (int m = 0; m < 8; ++m)
            hv[m] = *(const float4*)&hB[(iq << 5) + (m << 2)];

        float acc[8] = {0, 0, 0, 0, 0, 0, 0, 0};
#pragma unroll
        for (int m = 0; m < 32; ++m) {
            half8 b = *(const half8*)(bt + (m << 7));
            float s = (&hv[m >> 2].x)[m & 3];
#pragma unroll
            for (int j = 0; j < 8; ++j)
                acc[j] += s * (float)b[j];
        }
#pragma unroll
        for (int j = 0; j < 8; ++j) {
            float v = acc[j];
            v += __shfl_xor(v, 16);
            v += __shfl_xor(v, 32);
            acc[j] = v;
        }
        if (iq == 0) {
            *(float4*)&hB[(kg << 3)]     = make_float4(acc[0], acc[1], acc[2], acc[3]);
            *(float4*)&hB[(kg << 3) + 4] = make_float4(acc[4], acc[5], acc[6], acc[7]);
        }
        // next iteration's hB reads are RAW-ordered within the wave (no barrier)
    }

    if (!last) {
        float* hs = hstate + (n << 7);
        hs[lane] = hB[lane];
        hs[lane + 64] = hB[lane + 64];
    } else if (lane < 32) {
        float s = 0.f;
        for (int i2 = 0; i2 < 128; ++i2) s += hB[i2] * Om[(i2 << 5) + lane];
        out[(n << 5) + lane] = s;
    }
}

// ================= kernels =================
__global__ __launch_bounds__(256, 2)
void k_gemm(const f16* __restrict__ Af2, const f16* __restrict__ Xh,
            f16* __restrict__ B, int t0, int logTc) {
    __shared__ __align__(16) char smem[65536];
    gemm_body((f16*)smem, (f16*)(smem + 32768), Af2, Xh, B, t0, logTc,
              blockIdx.x, blockIdx.y, threadIdx.x);
}

__global__ __launch_bounds__(256, 2)
void k_chain(const f16* __restrict__ B, float* __restrict__ hstate,
             const float* __restrict__ alpha, const float* __restrict__ Om,
             float* __restrict__ out, int Tc, int first, int last) {
    __shared__ __align__(16) float hB[4][128];
    const int w = threadIdx.x >> 6;
    chain_wave(hB[w], B, hstate, alpha, Om, out, Tc, first, last,
               (blockIdx.x << 2) + w, threadIdx.x & 63);
}

// fused: blocks 0..31 run chain(c) (4 waves = 4 batches); blocks 32.. run gemm(c+1).
__global__ __launch_bounds__(256, 2)
void k_fused(const f16* __restrict__ Af2, const f16* __restrict__ Xh,
             f16* __restrict__ Bw, const f16* __restrict__ Br,
             float* __restrict__ hstate, const float* __restrict__ alpha,
             const float* __restrict__ Om, float* __restrict__ out,
             int t0g, int logTc, int Tc, int first, int last) {
    __shared__ __align__(16) char smem[65536];
    const int bx = blockIdx.x;
    if (bx < 32) {
        float* hB = (float*)(smem + ((threadIdx.x >> 6) << 9));
        chain_wave(hB, Br, hstate, alpha, Om, out, Tc, first, last,
                   (bx << 2) + (threadIdx.x >> 6), threadIdx.x & 63);
    } else {
        int g = bx - 32;
        int qtile = g & (Tc - 1);
        int i = g >> logTc;
        gemm_body((f16*)smem, (f16*)(smem + 32768), Af2, Xh, Bw, t0g, logTc,
                  qtile, i, threadIdx.x);
    }
}

extern "C" void kernel_launch(void* const* d_in, const int* in_sizes, int n_in,
                              void* d_out, int out_size, void* d_ws, size_t ws_size,
                              hipStream_t stream) {
    const float* x     = (const float*)d_in[0];
    const float* alpha = (const float*)d_in[1];
    const float* A     = (const float*)d_in[2];
    const float* Om    = (const float*)d_in[3];
    float* out = (float*)d_out;

    char* ws = (char*)d_ws;
    f16*   Af2    = (f16*)ws;                          // 4 MB  [i][k][j]
    f16*   Xh     = (f16*)(ws + ((size_t)4 << 20));    // 16 MB [n*512+t][j]
    float* hstate = (float*)(ws + ((size_t)20 << 20)); // 64 KB

    int Tc = 16;   // double-buffered: 2 x 64 MB -> LLC resident with X+A
    while (Tc > 4 && ((size_t)21 << 20) + (((size_t)Tc << 22) * 2) > ws_size) Tc >>= 1;
    int logTc = 31 - __builtin_clz(Tc);
    int nch = 512 / Tc;
    f16* Bc[2];
    Bc[0] = (f16*)(ws + ((size_t)21 << 20));
    Bc[1] = (f16*)(ws + ((size_t)21 << 20) + ((size_t)Tc << 22));

    k_cvt_x<<<8192, 256, 0, stream>>>(x, Xh);
    k_cvt_A<<<8192, 256, 0, stream>>>(A, Af2);

    // prologue: gemm chunk 0 -> Bc[0]
    k_gemm<<<dim3(Tc, 128), 256, 0, stream>>>(Af2, Xh, Bc[0], 0, logTc);

    for (int c = 0; c < nch; ++c) {
        const f16* br = Bc[c & 1];
        if (c + 1 < nch) {
            k_fused<<<32 + Tc * 128, 256, 0, stream>>>(
                Af2, Xh, Bc[(c + 1) & 1], br, hstate, alpha, Om, out,
                (c + 1) * Tc, logTc, Tc, c == 0, c == nch - 1);
        } else {
            k_chain<<<32, 256, 0, stream>>>(br, hstate, alpha, Om, out,
                                            Tc, c == 0, c == nch - 1);
        }
    }
    (void)in_sizes; (void)n_in; (void)out_size;
}